// Round 11
// baseline (304.430 us; speedup 1.0000x reference)
//
#include <hip/hip_runtime.h>
#include <hip/hip_bf16.h>

#define BB 8
#define SS 1024
#define DM 512
#define HH 8
#define BM 128
#define BN 128
#define BK 32
#define LD 40   // LDS row stride (bf16 elems): 80 B = 16B-aligned, 2-way banks

typedef __bf16 bf16x8 __attribute__((ext_vector_type(8)));
typedef __bf16 bf16x4 __attribute__((ext_vector_type(4)));
typedef float f32x4 __attribute__((ext_vector_type(4)));

__device__ __forceinline__ f32x4 mfma16(bf16x8 a, bf16x8 b, f32x4 c) {
    return __builtin_amdgcn_mfma_f32_16x16x32_bf16(a, b, c, 0, 0, 0);
}

// ---------------- W transpose + hi/lo split ----------------
__global__ __launch_bounds__(256) void wconv(
    const float* __restrict__ W0, const float* __restrict__ W1,
    const float* __restrict__ W2, const float* __restrict__ W3,
    __bf16* __restrict__ th, __bf16* __restrict__ tl)
{
    const float* W = blockIdx.z == 0 ? W0 : blockIdx.z == 1 ? W1
                   : blockIdx.z == 2 ? W2 : W3;
    __bf16* oh = th + (size_t)blockIdx.z * 512 * 512;
    __bf16* ol = tl + (size_t)blockIdx.z * 512 * 512;
    __shared__ float T[64][65];
    const int k0 = blockIdx.x * 64, n0 = blockIdx.y * 64;
    const int r = threadIdx.x >> 4, c4 = (threadIdx.x & 15) * 4;
    #pragma unroll
    for (int p = 0; p < 4; ++p) {
        float4 v = *(const float4*)(W + (size_t)(k0 + p * 16 + r) * 512 + n0 + c4);
        T[p * 16 + r][c4 + 0] = v.x; T[p * 16 + r][c4 + 1] = v.y;
        T[p * 16 + r][c4 + 2] = v.z; T[p * 16 + r][c4 + 3] = v.w;
    }
    __syncthreads();
    #pragma unroll
    for (int p = 0; p < 4; ++p) {
        int n = n0 + p * 16 + r;
        bf16x4 h4, l4;
        #pragma unroll
        for (int j = 0; j < 4; ++j) {
            float x = T[c4 + j][p * 16 + r];
            __bf16 h = (__bf16)x;
            h4[j] = h; l4[j] = (__bf16)(x - (float)h);
        }
        *(bf16x4*)(oh + (size_t)n * 512 + k0 + c4) = h4;
        *(bf16x4*)(ol + (size_t)n * 512 + k0 + c4) = l4;
    }
}

// ---------------- LDS-staged tile GEMM ----------------
template<int MODE>
__global__ __launch_bounds__(256, 3) void gemm_tile(
    const float* __restrict__ Aq, const float* __restrict__ Ak,
    const float* __restrict__ Av,
    const __bf16* __restrict__ Ahig, const __bf16* __restrict__ Alog,
    const __bf16* __restrict__ Wth, const __bf16* __restrict__ Wtl,
    const float* __restrict__ bq, const float* __restrict__ bk,
    const float* __restrict__ bv,
    float* __restrict__ Cf, __bf16* __restrict__ qo, __bf16* __restrict__ ko,
    __bf16* __restrict__ vo)
{
    __shared__ __align__(16) __bf16 Ah[BM][LD];
    __shared__ __align__(16) __bf16 Al[(MODE == 1 ? BM : 1)][LD];
    __shared__ __align__(16) __bf16 Bh[BN][LD];
    __shared__ __align__(16) __bf16 Bl[BN][LD];

    const int tid = threadIdx.x;
    const int w = tid >> 6, lane = tid & 63, l15 = lane & 15, lg = lane >> 4;
    const int wm = w >> 1, wn = w & 1;
    const int bx = blockIdx.x;
    const int z  = MODE == 0 ? (bx >> 2) : 3;
    const int n0 = MODE == 0 ? (bx & 3) * BN : bx * BN;
    const int m0 = blockIdx.y * BM;

    const float* Afp = (MODE == 0) ? (z == 0 ? Aq : z == 1 ? Ak : Av) : nullptr;
    const __bf16* wh = Wth + (size_t)z * 512 * 512;
    const __bf16* wl = Wtl + (size_t)z * 512 * 512;

    f32x4 acc[4][4];
    #pragma unroll
    for (int i = 0; i < 4; ++i)
        #pragma unroll
        for (int j = 0; j < 4; ++j) acc[i][j] = (f32x4){0.f, 0.f, 0.f, 0.f};

    for (int k0 = 0; k0 < 512; k0 += BK) {
        __syncthreads();
        if (MODE == 0) {
            const int row = tid >> 3, c = (tid & 7) * 4;
            #pragma unroll
            for (int p = 0; p < 4; ++p) {
                int rr = row + p * 32;
                f32x4 a = *(const f32x4*)(Afp + (size_t)(m0 + rr) * 512 + k0 + c);
                bf16x4 h4;
                #pragma unroll
                for (int j = 0; j < 4; ++j) h4[j] = (__bf16)a[j];
                *(bf16x4*)&Ah[rr][c] = h4;
            }
        } else {
            const int row = tid >> 2, c = (tid & 3) * 8;
            #pragma unroll
            for (int p = 0; p < 2; ++p) {
                int rr = row + p * 64;
                *(bf16x8*)&Ah[rr][c] =
                    *(const bf16x8*)(Ahig + (size_t)(m0 + rr) * 512 + k0 + c);
                *(bf16x8*)&Al[rr][c] =
                    *(const bf16x8*)(Alog + (size_t)(m0 + rr) * 512 + k0 + c);
            }
        }
        {
            const int row = tid >> 2, c = (tid & 3) * 8;
            #pragma unroll
            for (int p = 0; p < 2; ++p) {
                int rr = row + p * 64;
                *(bf16x8*)&Bh[rr][c] =
                    *(const bf16x8*)(wh + (size_t)(n0 + rr) * 512 + k0 + c);
                *(bf16x8*)&Bl[rr][c] =
                    *(const bf16x8*)(wl + (size_t)(n0 + rr) * 512 + k0 + c);
            }
        }
        __syncthreads();

        bf16x8 afh[4], afl[4];
        #pragma unroll
        for (int mt = 0; mt < 4; ++mt) {
            afh[mt] = *(const bf16x8*)&Ah[wm * 64 + mt * 16 + l15][lg * 8];
            if (MODE == 1)
                afl[mt] = *(const bf16x8*)&Al[wm * 64 + mt * 16 + l15][lg * 8];
        }
        #pragma unroll
        for (int nt = 0; nt < 4; ++nt) {
            bf16x8 bfh = *(const bf16x8*)&Bh[wn * 64 + nt * 16 + l15][lg * 8];
            bf16x8 bfl = *(const bf16x8*)&Bl[wn * 64 + nt * 16 + l15][lg * 8];
            #pragma unroll
            for (int mt = 0; mt < 4; ++mt) {
                acc[mt][nt] = mfma16(afh[mt], bfh, acc[mt][nt]);
                acc[mt][nt] = mfma16(afh[mt], bfl, acc[mt][nt]);
                if (MODE == 1)
                    acc[mt][nt] = mfma16(afl[mt], bfh, acc[mt][nt]);
            }
        }
    }

    const float* bias = (MODE == 1) ? bq : (z == 0 ? bq : z == 1 ? bk : bv);
    #pragma unroll
    for (int nt = 0; nt < 4; ++nt) {
        const int n = n0 + wn * 64 + nt * 16 + l15;
        const float bz = bias[n];
        #pragma unroll
        for (int mt = 0; mt < 4; ++mt) {
            if (MODE == 0 && z == 2) {
                bf16x4 v4;
                int mbase = m0 + wm * 64 + mt * 16 + lg * 4;
                #pragma unroll
                for (int rr = 0; rr < 4; ++rr)
                    v4[rr] = (__bf16)(acc[mt][nt][rr] + bz);
                int bb = mbase >> 10, s = mbase & 1023, h = n >> 6, d = n & 63;
                *(bf16x4*)(vo + ((size_t)(bb * HH + h) * 64 + d) * SS + s) = v4;
            } else {
                #pragma unroll
                for (int rr = 0; rr < 4; ++rr) {
                    int m = m0 + wm * 64 + mt * 16 + lg * 4 + rr;
                    float v = acc[mt][nt][rr] + bz;
                    if (MODE == 1) {
                        Cf[(size_t)m * 512 + n] = v;
                    } else {
                        int bb = m >> 10, s = m & 1023, h = n >> 6, d = n & 63;
                        __bf16* outp = z == 0 ? qo : ko;
                        outp[((size_t)(bb * HH + h) * SS + s) * 64 + d] = (__bf16)v;
                    }
                }
            }
        }
    }
}

// ---------------- G precompute ----------------
__global__ __launch_bounds__(256) void gprep(
    const float* __restrict__ mask, const float* __restrict__ adj,
    const float* __restrict__ dist,
    __bf16* __restrict__ Gg, float* __restrict__ rowILg)
{
    const int w = threadIdx.x >> 6, lane = threadIdx.x & 63;
    const int row = blockIdx.x * 4 + w;
    const int b = row >> 10;
    const size_t drow = (size_t)row * SS;
    const float L2E = 1.44269504f;
    const float* mrow = mask + (size_t)b * SS;
    float sm = 0.f;
    #pragma unroll
    for (int j = 0; j < 4; ++j) {
        int c = lane * 4 + j * 256;
        f32x4 d4 = *(const f32x4*)(dist + drow + c);
        f32x4 a4 = *(const f32x4*)(adj + drow + c);
        f32x4 m4 = *(const f32x4*)(mrow + c);
        bf16x4 g4;
        #pragma unroll
        for (int r = 0; r < 4; ++r) {
            float e = exp2f(fmaf(m4[r], -1e9f * L2E, fmaf(d4[r], L2E, -L2E)));
            sm += e;
            g4[r] = (__bf16)(a4[r] * e);
        }
        *(bf16x4*)(Gg + drow + c) = g4;
    }
    #pragma unroll
    for (int off = 1; off <= 32; off <<= 1)
        sm += __shfl_xor(sm, off, 64);
    if (lane == 0) rowILg[row] = 1.0f / sm;
}

// ---------------- Fused attention v7: 2-pass QK, phase-split 16KB P, 7 blk/CU ----------------
// grid 4096 flat: b = bid&7, h = (bid>>3)&7, qt = bid>>6. 256 thr = 4 waves.
__global__ __launch_bounds__(256, 7) void attn7(
    const __bf16* __restrict__ qh, const __bf16* __restrict__ kh,
    const __bf16* __restrict__ vt,
    const float* __restrict__ mask, const __bf16* __restrict__ Gg,
    const float* __restrict__ rowILg,
    float* __restrict__ attn_out, __bf16* __restrict__ chi, __bf16* __restrict__ clo)
{
    __shared__ float nmb[1024];
    __shared__ __align__(16) __bf16 P[16][512];   // one 512-key phase; XOR swizzle
    __shared__ float redl[4][16];

    const int tid = threadIdx.x;
    const int w = tid >> 6, lane = tid & 63, l15 = lane & 15, lg = lane >> 4;
    const int bid = blockIdx.x;
    const int b = bid & 7;
    const int h = (bid >> 3) & 7;
    const int q0 = (bid >> 6) * 16;
    const float L2E = 1.44269504f;
    const float c1 = 0.125f * L2E;

    char* Pb = (char*)P;
    #define PADDR(row, bytes) (Pb + (row) * 1024 + ((bytes) ^ (((row) & 7) << 4)))

    {
        f32x4 m4 = *(const f32x4*)(mask + (size_t)b * SS + tid * 4);
        f32x4 n4;
        #pragma unroll
        for (int r = 0; r < 4; ++r)
            n4[r] = fmaf(m4[r], -1e9f * L2E, -16.0f * L2E);
        *(f32x4*)&nmb[tid * 4] = n4;
    }
    __syncthreads();

    const size_t hb = ((size_t)(b * HH + h)) * SS * 64;
    bf16x8 qf[2];
    #pragma unroll
    for (int ks = 0; ks < 2; ++ks)
        qf[ks] = *(const bf16x8*)(qh + hb + (size_t)(q0 + l15) * 64 + ks * 32 + lg * 8);
    const __bf16* kbp = kh + hb + (size_t)l15 * 64 + lg * 8;   // + kt*1024
    const __bf16* gbp = Gg + ((size_t)b * SS + q0 + l15) * SS; // + key

    // ---- pass 1: denominator only, wave w covers keys [256w, 256w+256) ----
    float lac0 = 0.f, lac1 = 0.f, lac2 = 0.f, lac3 = 0.f;
    #pragma unroll
    for (int nt = 0; nt < 16; ++nt) {
        const int kt = w * 16 + nt;
        bf16x8 k0v = *(const bf16x8*)(kbp + (size_t)kt * 1024);
        bf16x8 k1v = *(const bf16x8*)(kbp + (size_t)kt * 1024 + 32);
        f32x4 acc = {0.f, 0.f, 0.f, 0.f};
        acc = mfma16(k0v, qf[0], acc);
        acc = mfma16(k1v, qf[1], acc);
        f32x4 nb4 = *(const f32x4*)&nmb[kt * 16 + lg * 4];
        lac0 += exp2f(fmaf(acc[0], c1, nb4[0]));
        lac1 += exp2f(fmaf(acc[1], c1, nb4[1]));
        lac2 += exp2f(fmaf(acc[2], c1, nb4[2]));
        lac3 += exp2f(fmaf(acc[3], c1, nb4[3]));
    }
    float l = (lac0 + lac1) + (lac2 + lac3);
    #pragma unroll
    for (int off = 16; off <= 32; off <<= 1)
        l += __shfl_xor(l, off, 64);
    if (lg == 0) redl[w][l15] = l;
    __syncthreads();

    // per-lane coef for q = l15 (folded into P below)
    const float* rg = rowILg + (size_t)b * SS + q0;
    const float ltot = redl[0][l15] + redl[1][l15] + redl[2][l15] + redl[3][l15];
    const float coefQ = rg[l15] / ltot;

    f32x4 cacc = {0.f, 0.f, 0.f, 0.f};
    float* aoutb = attn_out + ((size_t)(b * HH + h)) * SS * SS;
    const __bf16* vb = vt + ((size_t)(b * HH + h) * 64 + w * 16 + l15) * SS + lg * 8;

    // ---- pass 2: two 512-key phases through the 16KB P buffer ----
    for (int ph = 0; ph < 2; ++ph) {
        // QK^T: wave w covers keys [ph*512 + w*128, +128) = 8 n-tiles
        #pragma unroll
        for (int nt2 = 0; nt2 < 8; ++nt2) {
            const int kt = ph * 32 + w * 8 + nt2;
            bf16x8 k0v = *(const bf16x8*)(kbp + (size_t)kt * 1024);
            bf16x8 k1v = *(const bf16x8*)(kbp + (size_t)kt * 1024 + 32);
            f32x4 acc = {0.f, 0.f, 0.f, 0.f};
            acc = mfma16(k0v, qf[0], acc);
            acc = mfma16(k1v, qf[1], acc);
            f32x4 nb4 = *(const f32x4*)&nmb[kt * 16 + lg * 4];
            bf16x4 g4 = *(const bf16x4*)(gbp + kt * 16 + lg * 4);
            bf16x4 pb;
            pb[0] = (__bf16)(exp2f(fmaf(acc[0], c1, nb4[0])) * coefQ * (float)g4[0]);
            pb[1] = (__bf16)(exp2f(fmaf(acc[1], c1, nb4[1])) * coefQ * (float)g4[1]);
            pb[2] = (__bf16)(exp2f(fmaf(acc[2], c1, nb4[2])) * coefQ * (float)g4[2]);
            pb[3] = (__bf16)(exp2f(fmaf(acc[3], c1, nb4[3])) * coefQ * (float)g4[3]);
            *(bf16x4*)PADDR(l15, kt * 32 + lg * 8 - ph * 1024) = pb;
        }
        __syncthreads();

        // attn write: wave w -> q-rows [4w, 4w+4), keys [ph*512, +512)
        #pragma unroll
        for (int r = 0; r < 4; ++r) {
            const int row = w * 4 + r;
            float* ar = aoutb + (size_t)(q0 + row) * SS + ph * 512;
            #pragma unroll
            for (int j = 0; j < 2; ++j) {
                const int bytes = lane * 8 + j * 512;
                bf16x4 pb = *(const bf16x4*)PADDR(row, bytes);
                f32x4 av;
                #pragma unroll
                for (int r2 = 0; r2 < 4; ++r2) av[r2] = (float)pb[r2];
                __builtin_nontemporal_store(av, (f32x4*)(ar + (bytes >> 1)));
            }
        }

        // PV: wave w owns d-cols [16w,16w+16), keys [ph*512, +512)
        #pragma unroll
        for (int c2 = 0; c2 < 16; ++c2) {
            bf16x8 pa = *(const bf16x8*)PADDR(l15, c2 * 64 + lg * 16);
            bf16x8 vv = *(const bf16x8*)(vb + (ph * 16 + c2) * 32);
            cacc = mfma16(pa, vv, cacc);
        }
        __syncthreads();
    }

    // ---- epilogue: coef already folded into P; write ctx hi/lo ----
    #pragma unroll
    for (int r = 0; r < 4; ++r) {
        const int row = lg * 4 + r;
        float x = cacc[r];
        __bf16 hv = (__bf16)x;
        size_t idx = ((size_t)b * SS + q0 + row) * DM + h * 64 + w * 16 + l15;
        chi[idx] = hv;
        clo[idx] = (__bf16)(x - (float)hv);
    }
    #undef PADDR
}

extern "C" void kernel_launch(void* const* d_in, const int* in_sizes, int n_in,
                              void* d_out, int out_size, void* d_ws, size_t ws_size,
                              hipStream_t stream) {
    const float* q    = (const float*)d_in[0];
    const float* k    = (const float*)d_in[1];
    const float* v    = (const float*)d_in[2];
    const float* mask = (const float*)d_in[3];
    const float* adj  = (const float*)d_in[4];
    const float* dist = (const float*)d_in[5];
    const float* Wq   = (const float*)d_in[6];
    const float* bq   = (const float*)d_in[7];
    const float* Wk   = (const float*)d_in[8];
    const float* bk   = (const float*)d_in[9];
    const float* Wv   = (const float*)d_in[10];
    const float* bv   = (const float*)d_in[11];
    const float* Wo   = (const float*)d_in[12];
    const float* bo   = (const float*)d_in[13];

    const size_t NT = (size_t)BB * SS * DM;   // 4,194,304
    const size_t WN = 512 * 512;
    const size_t NSS = (size_t)BB * SS * SS;  // 8,388,608
    __bf16* wth = (__bf16*)d_ws;
    __bf16* wtl = wth + 4 * WN;
    __bf16* qhb = wtl + 4 * WN;
    __bf16* khb = qhb + NT;
    __bf16* vtb = khb + NT;
    __bf16* chi = vtb + NT;
    __bf16* clo = chi + NT;
    __bf16* Gg  = clo + NT;
    float* rowILg = (float*)(Gg + NSS);

    float* outp = (float*)d_out;
    float* attn = outp + NT;

    wconv<<<dim3(8, 8, 4), 256, 0, stream>>>(Wq, Wk, Wv, Wo, wth, wtl);

    gprep<<<2048, 256, 0, stream>>>(mask, adj, dist, Gg, rowILg);

    gemm_tile<0><<<dim3(12, 64), 256, 0, stream>>>(
        q, k, v, nullptr, nullptr, wth, wtl, bq, bk, bv,
        nullptr, qhb, khb, vtb);

    attn7<<<4096, 256, 0, stream>>>(qhb, khb, vtb, mask, Gg, rowILg, attn, chi, clo);

    gemm_tile<1><<<dim3(4, 64), 256, 0, stream>>>(
        nullptr, nullptr, nullptr, chi, clo, wth, wtl, bo, nullptr, nullptr,
        outp, nullptr, nullptr, nullptr);
}

// Round 12
// 244.536 us; speedup vs baseline: 1.2449x; 1.2449x over previous
//
#include <hip/hip_runtime.h>
#include <hip/hip_bf16.h>

#define BB 8
#define SS 1024
#define DM 512
#define HH 8
#define BM 128
#define BN 128
#define BK 32
#define LD 40   // LDS row stride (bf16 elems): 80 B = 16B-aligned, 2-way banks

typedef __bf16 bf16x8 __attribute__((ext_vector_type(8)));
typedef __bf16 bf16x4 __attribute__((ext_vector_type(4)));
typedef float f32x4 __attribute__((ext_vector_type(4)));

__device__ __forceinline__ f32x4 mfma16(bf16x8 a, bf16x8 b, f32x4 c) {
    return __builtin_amdgcn_mfma_f32_16x16x32_bf16(a, b, c, 0, 0, 0);
}

// ---------------- W transpose + hi/lo split ----------------
__global__ __launch_bounds__(256) void wconv(
    const float* __restrict__ W0, const float* __restrict__ W1,
    const float* __restrict__ W2, const float* __restrict__ W3,
    __bf16* __restrict__ th, __bf16* __restrict__ tl)
{
    const float* W = blockIdx.z == 0 ? W0 : blockIdx.z == 1 ? W1
                   : blockIdx.z == 2 ? W2 : W3;
    __bf16* oh = th + (size_t)blockIdx.z * 512 * 512;
    __bf16* ol = tl + (size_t)blockIdx.z * 512 * 512;
    __shared__ float T[64][65];
    const int k0 = blockIdx.x * 64, n0 = blockIdx.y * 64;
    const int r = threadIdx.x >> 4, c4 = (threadIdx.x & 15) * 4;
    #pragma unroll
    for (int p = 0; p < 4; ++p) {
        float4 v = *(const float4*)(W + (size_t)(k0 + p * 16 + r) * 512 + n0 + c4);
        T[p * 16 + r][c4 + 0] = v.x; T[p * 16 + r][c4 + 1] = v.y;
        T[p * 16 + r][c4 + 2] = v.z; T[p * 16 + r][c4 + 3] = v.w;
    }
    __syncthreads();
    #pragma unroll
    for (int p = 0; p < 4; ++p) {
        int n = n0 + p * 16 + r;
        bf16x4 h4, l4;
        #pragma unroll
        for (int j = 0; j < 4; ++j) {
            float x = T[c4 + j][p * 16 + r];
            __bf16 h = (__bf16)x;
            h4[j] = h; l4[j] = (__bf16)(x - (float)h);
        }
        *(bf16x4*)(oh + (size_t)n * 512 + k0 + c4) = h4;
        *(bf16x4*)(ol + (size_t)n * 512 + k0 + c4) = l4;
    }
}

// ---------------- LDS-staged tile GEMM ----------------
template<int MODE>
__global__ __launch_bounds__(256, 3) void gemm_tile(
    const float* __restrict__ Aq, const float* __restrict__ Ak,
    const float* __restrict__ Av,
    const __bf16* __restrict__ Ahig, const __bf16* __restrict__ Alog,
    const __bf16* __restrict__ Wth, const __bf16* __restrict__ Wtl,
    const float* __restrict__ bq, const float* __restrict__ bk,
    const float* __restrict__ bv,
    float* __restrict__ Cf, __bf16* __restrict__ qo, __bf16* __restrict__ ko,
    __bf16* __restrict__ vo)
{
    __shared__ __align__(16) __bf16 Ah[BM][LD];
    __shared__ __align__(16) __bf16 Al[(MODE == 1 ? BM : 1)][LD];
    __shared__ __align__(16) __bf16 Bh[BN][LD];
    __shared__ __align__(16) __bf16 Bl[BN][LD];

    const int tid = threadIdx.x;
    const int w = tid >> 6, lane = tid & 63, l15 = lane & 15, lg = lane >> 4;
    const int wm = w >> 1, wn = w & 1;
    const int bx = blockIdx.x;
    const int z  = MODE == 0 ? (bx >> 2) : 3;
    const int n0 = MODE == 0 ? (bx & 3) * BN : bx * BN;
    const int m0 = blockIdx.y * BM;

    const float* Afp = (MODE == 0) ? (z == 0 ? Aq : z == 1 ? Ak : Av) : nullptr;
    const __bf16* wh = Wth + (size_t)z * 512 * 512;
    const __bf16* wl = Wtl + (size_t)z * 512 * 512;

    f32x4 acc[4][4];
    #pragma unroll
    for (int i = 0; i < 4; ++i)
        #pragma unroll
        for (int j = 0; j < 4; ++j) acc[i][j] = (f32x4){0.f, 0.f, 0.f, 0.f};

    for (int k0 = 0; k0 < 512; k0 += BK) {
        __syncthreads();
        if (MODE == 0) {
            const int row = tid >> 3, c = (tid & 7) * 4;
            #pragma unroll
            for (int p = 0; p < 4; ++p) {
                int rr = row + p * 32;
                f32x4 a = *(const f32x4*)(Afp + (size_t)(m0 + rr) * 512 + k0 + c);
                bf16x4 h4;
                #pragma unroll
                for (int j = 0; j < 4; ++j) h4[j] = (__bf16)a[j];
                *(bf16x4*)&Ah[rr][c] = h4;
            }
        } else {
            const int row = tid >> 2, c = (tid & 3) * 8;
            #pragma unroll
            for (int p = 0; p < 2; ++p) {
                int rr = row + p * 64;
                *(bf16x8*)&Ah[rr][c] =
                    *(const bf16x8*)(Ahig + (size_t)(m0 + rr) * 512 + k0 + c);
                *(bf16x8*)&Al[rr][c] =
                    *(const bf16x8*)(Alog + (size_t)(m0 + rr) * 512 + k0 + c);
            }
        }
        {
            const int row = tid >> 2, c = (tid & 3) * 8;
            #pragma unroll
            for (int p = 0; p < 2; ++p) {
                int rr = row + p * 64;
                *(bf16x8*)&Bh[rr][c] =
                    *(const bf16x8*)(wh + (size_t)(n0 + rr) * 512 + k0 + c);
                *(bf16x8*)&Bl[rr][c] =
                    *(const bf16x8*)(wl + (size_t)(n0 + rr) * 512 + k0 + c);
            }
        }
        __syncthreads();

        bf16x8 afh[4], afl[4];
        #pragma unroll
        for (int mt = 0; mt < 4; ++mt) {
            afh[mt] = *(const bf16x8*)&Ah[wm * 64 + mt * 16 + l15][lg * 8];
            if (MODE == 1)
                afl[mt] = *(const bf16x8*)&Al[wm * 64 + mt * 16 + l15][lg * 8];
        }
        #pragma unroll
        for (int nt = 0; nt < 4; ++nt) {
            bf16x8 bfh = *(const bf16x8*)&Bh[wn * 64 + nt * 16 + l15][lg * 8];
            bf16x8 bfl = *(const bf16x8*)&Bl[wn * 64 + nt * 16 + l15][lg * 8];
            #pragma unroll
            for (int mt = 0; mt < 4; ++mt) {
                acc[mt][nt] = mfma16(afh[mt], bfh, acc[mt][nt]);
                acc[mt][nt] = mfma16(afh[mt], bfl, acc[mt][nt]);
                if (MODE == 1)
                    acc[mt][nt] = mfma16(afl[mt], bfh, acc[mt][nt]);
            }
        }
    }

    const float* bias = (MODE == 1) ? bq : (z == 0 ? bq : z == 1 ? bk : bv);
    #pragma unroll
    for (int nt = 0; nt < 4; ++nt) {
        const int n = n0 + wn * 64 + nt * 16 + l15;
        const float bz = bias[n];
        #pragma unroll
        for (int mt = 0; mt < 4; ++mt) {
            if (MODE == 0 && z == 2) {
                bf16x4 v4;
                int mbase = m0 + wm * 64 + mt * 16 + lg * 4;
                #pragma unroll
                for (int rr = 0; rr < 4; ++rr)
                    v4[rr] = (__bf16)(acc[mt][nt][rr] + bz);
                int bb = mbase >> 10, s = mbase & 1023, h = n >> 6, d = n & 63;
                *(bf16x4*)(vo + ((size_t)(bb * HH + h) * 64 + d) * SS + s) = v4;
            } else {
                #pragma unroll
                for (int rr = 0; rr < 4; ++rr) {
                    int m = m0 + wm * 64 + mt * 16 + lg * 4 + rr;
                    float v = acc[mt][nt][rr] + bz;
                    if (MODE == 1) {
                        Cf[(size_t)m * 512 + n] = v;
                    } else {
                        int bb = m >> 10, s = m & 1023, h = n >> 6, d = n & 63;
                        __bf16* outp = z == 0 ? qo : ko;
                        outp[((size_t)(bb * HH + h) * SS + s) * 64 + d] = (__bf16)v;
                    }
                }
            }
        }
    }
}

// ---------------- G precompute ----------------
__global__ __launch_bounds__(256) void gprep(
    const float* __restrict__ mask, const float* __restrict__ adj,
    const float* __restrict__ dist,
    __bf16* __restrict__ Gg, float* __restrict__ rowILg)
{
    const int w = threadIdx.x >> 6, lane = threadIdx.x & 63;
    const int row = blockIdx.x * 4 + w;
    const int b = row >> 10;
    const size_t drow = (size_t)row * SS;
    const float L2E = 1.44269504f;
    const float* mrow = mask + (size_t)b * SS;
    float sm = 0.f;
    #pragma unroll
    for (int j = 0; j < 4; ++j) {
        int c = lane * 4 + j * 256;
        f32x4 d4 = *(const f32x4*)(dist + drow + c);
        f32x4 a4 = *(const f32x4*)(adj + drow + c);
        f32x4 m4 = *(const f32x4*)(mrow + c);
        bf16x4 g4;
        #pragma unroll
        for (int r = 0; r < 4; ++r) {
            float e = exp2f(fmaf(m4[r], -1e9f * L2E, fmaf(d4[r], L2E, -L2E)));
            sm += e;
            g4[r] = (__bf16)(a4[r] * e);
        }
        *(bf16x4*)(Gg + drow + c) = g4;
    }
    #pragma unroll
    for (int off = 1; off <= 32; off <<= 1)
        sm += __shfl_xor(sm, off, 64);
    if (lane == 0) rowILg[row] = 1.0f / sm;
}

// ---------------- Fused attention v6b: head->XCD mapping (L2 fit) ----------------
// grid 4096 flat: h = bid&7 (XCD = h: per-XCD K/V = 8 batches x 256KB = 2MB, fits
// 4MB L2; old b-pinning put 6.3MB on one L2 -> thrash), b = (bid>>3)&7, qt = bid>>6.
__global__ __launch_bounds__(256, 4) void attn6(
    const __bf16* __restrict__ qh, const __bf16* __restrict__ kh,
    const __bf16* __restrict__ vt,
    const float* __restrict__ mask, const __bf16* __restrict__ Gg,
    const float* __restrict__ rowILg,
    float* __restrict__ attn_out, __bf16* __restrict__ chi, __bf16* __restrict__ clo)
{
    __shared__ float nmb[1024];
    __shared__ __align__(16) __bf16 P[16][1024];   // XOR-swizzled: byte ^= (row&7)<<4
    __shared__ float redl[4][16];

    const int tid = threadIdx.x;
    const int w = tid >> 6, lane = tid & 63, l15 = lane & 15, lg = lane >> 4;
    const int bid = blockIdx.x;
    const int h = bid & 7;            // XCD pin: head -> XCD
    const int b = (bid >> 3) & 7;
    const int q0 = (bid >> 6) * 16;
    const float L2E = 1.44269504f;
    const float c1 = 0.125f * L2E;

    char* Pb = (char*)P;
    #define PADDR(row, bytes) (Pb + (row) * 2048 + ((bytes) ^ (((row) & 7) << 4)))

    {
        f32x4 m4 = *(const f32x4*)(mask + (size_t)b * SS + tid * 4);
        f32x4 n4;
        #pragma unroll
        for (int r = 0; r < 4; ++r)
            n4[r] = fmaf(m4[r], -1e9f * L2E, -16.0f * L2E);
        *(f32x4*)&nmb[tid * 4] = n4;
    }
    __syncthreads();

    const size_t hb = ((size_t)(b * HH + h)) * SS * 64;
    bf16x8 qf[2];
    #pragma unroll
    for (int ks = 0; ks < 2; ++ks)
        qf[ks] = *(const bf16x8*)(qh + hb + (size_t)(q0 + l15) * 64 + ks * 32 + lg * 8);
    const __bf16* kp = kh + hb + (size_t)(w * 256 + l15) * 64 + lg * 8;
    const __bf16* gp = Gg + ((size_t)b * SS + q0 + l15) * SS;

    // ---- pass 1: QK^T over this wave's 256 keys, depth-4 K/G pipeline ----
    float lac0 = 0.f, lac1 = 0.f, lac2 = 0.f, lac3 = 0.f;
    bf16x8 ks0[4], ks1[4];
    bf16x4 gs[4];
    #pragma unroll
    for (int i = 0; i < 4; ++i) {
        ks0[i] = *(const bf16x8*)(kp + (size_t)i * 1024);
        ks1[i] = *(const bf16x8*)(kp + (size_t)i * 1024 + 32);
        gs[i]  = *(const bf16x4*)(gp + (w * 16 + i) * 16 + lg * 4);
    }
    #pragma unroll
    for (int nt = 0; nt < 16; ++nt) {
        const int sl = nt & 3;
        bf16x8 k0v = ks0[sl], k1v = ks1[sl];
        bf16x4 g4 = gs[sl];
        if (nt + 4 < 16) {
            ks0[sl] = *(const bf16x8*)(kp + (size_t)(nt + 4) * 1024);
            ks1[sl] = *(const bf16x8*)(kp + (size_t)(nt + 4) * 1024 + 32);
            gs[sl]  = *(const bf16x4*)(gp + (w * 16 + nt + 4) * 16 + lg * 4);
        }
        const int kt = w * 16 + nt;
        f32x4 acc = {0.f, 0.f, 0.f, 0.f};
        acc = mfma16(k0v, qf[0], acc);
        acc = mfma16(k1v, qf[1], acc);
        f32x4 nb4 = *(const f32x4*)&nmb[kt * 16 + lg * 4];
        float e0 = exp2f(fmaf(acc[0], c1, nb4[0]));
        float e1 = exp2f(fmaf(acc[1], c1, nb4[1]));
        float e2 = exp2f(fmaf(acc[2], c1, nb4[2]));
        float e3 = exp2f(fmaf(acc[3], c1, nb4[3]));
        lac0 += e0; lac1 += e1; lac2 += e2; lac3 += e3;
        bf16x4 pb;
        pb[0] = (__bf16)(e0 * (float)g4[0]);
        pb[1] = (__bf16)(e1 * (float)g4[1]);
        pb[2] = (__bf16)(e2 * (float)g4[2]);
        pb[3] = (__bf16)(e3 * (float)g4[3]);
        *(bf16x4*)PADDR(l15, kt * 32 + lg * 8) = pb;
    }
    float l = (lac0 + lac1) + (lac2 + lac3);
    #pragma unroll
    for (int off = 16; off <= 32; off <<= 1)
        l += __shfl_xor(l, off, 64);
    if (lg == 0) redl[w][l15] = l;
    __syncthreads();

    // ---- attn write: wave w -> q-rows [4w, 4w+4) ----
    const float* rg = rowILg + (size_t)b * SS + q0;
    float* aoutb = attn_out + ((size_t)(b * HH + h)) * SS * SS;
    #pragma unroll
    for (int r = 0; r < 4; ++r) {
        const int row = w * 4 + r;
        const float ltot = redl[0][row] + redl[1][row] + redl[2][row] + redl[3][row];
        const float coefR = rg[row] / ltot;
        float* ar = aoutb + (size_t)(q0 + row) * SS;
        #pragma unroll
        for (int j = 0; j < 4; ++j) {
            bf16x4 pb = *(const bf16x4*)PADDR(row, lane * 8 + j * 512);
            f32x4 av;
            #pragma unroll
            for (int r2 = 0; r2 < 4; ++r2) av[r2] = (float)pb[r2] * coefR;
            __builtin_nontemporal_store(av, (f32x4*)(ar + ((lane * 8 + j * 512) >> 1)));
        }
    }

    // ---- PV: wave w owns d-cols [16w,16w+16), depth-4 V pipeline ----
    f32x4 cacc = {0.f, 0.f, 0.f, 0.f};
    const __bf16* vb = vt + ((size_t)(b * HH + h) * 64 + w * 16 + l15) * SS + lg * 8;
    bf16x8 vs[4];
    #pragma unroll
    for (int i = 0; i < 4; ++i) vs[i] = *(const bf16x8*)(vb + i * 32);
    #pragma unroll
    for (int c = 0; c < 32; ++c) {
        const int sl = c & 3;
        bf16x8 vv = vs[sl];
        if (c + 4 < 32) vs[sl] = *(const bf16x8*)(vb + (c + 4) * 32);
        bf16x8 pa = *(const bf16x8*)PADDR(l15, c * 64 + lg * 16);
        cacc = mfma16(pa, vv, cacc);
    }

    // ---- epilogue ----
    #pragma unroll
    for (int r = 0; r < 4; ++r) {
        const int row = lg * 4 + r;
        const float ltot = redl[0][row] + redl[1][row] + redl[2][row] + redl[3][row];
        const float coefE = rg[row] / ltot;
        float x = cacc[r] * coefE;
        __bf16 hv = (__bf16)x;
        size_t idx = ((size_t)b * SS + q0 + row) * DM + h * 64 + w * 16 + l15;
        chi[idx] = hv;
        clo[idx] = (__bf16)(x - (float)hv);
    }
    #undef PADDR
}

extern "C" void kernel_launch(void* const* d_in, const int* in_sizes, int n_in,
                              void* d_out, int out_size, void* d_ws, size_t ws_size,
                              hipStream_t stream) {
    const float* q    = (const float*)d_in[0];
    const float* k    = (const float*)d_in[1];
    const float* v    = (const float*)d_in[2];
    const float* mask = (const float*)d_in[3];
    const float* adj  = (const float*)d_in[4];
    const float* dist = (const float*)d_in[5];
    const float* Wq   = (const float*)d_in[6];
    const float* bq   = (const float*)d_in[7];
    const float* Wk   = (const float*)d_in[8];
    const float* bk   = (const float*)d_in[9];
    const float* Wv   = (const float*)d_in[10];
    const float* bv   = (const float*)d_in[11];
    const float* Wo   = (const float*)d_in[12];
    const float* bo   = (const float*)d_in[13];

    const size_t NT = (size_t)BB * SS * DM;   // 4,194,304
    const size_t WN = 512 * 512;
    const size_t NSS = (size_t)BB * SS * SS;  // 8,388,608
    __bf16* wth = (__bf16*)d_ws;
    __bf16* wtl = wth + 4 * WN;
    __bf16* qhb = wtl + 4 * WN;
    __bf16* khb = qhb + NT;
    __bf16* vtb = khb + NT;
    __bf16* chi = vtb + NT;
    __bf16* clo = chi + NT;
    __bf16* Gg  = clo + NT;
    float* rowILg = (float*)(Gg + NSS);

    float* outp = (float*)d_out;
    float* attn = outp + NT;

    wconv<<<dim3(8, 8, 4), 256, 0, stream>>>(Wq, Wk, Wv, Wo, wth, wtl);

    gprep<<<2048, 256, 0, stream>>>(mask, adj, dist, Gg, rowILg);

    gemm_tile<0><<<dim3(12, 64), 256, 0, stream>>>(
        q, k, v, nullptr, nullptr, wth, wtl, bq, bk, bv,
        nullptr, qhb, khb, vtb);

    attn6<<<4096, 256, 0, stream>>>(qhb, khb, vtb, mask, Gg, rowILg, attn, chi, clo);

    gemm_tile<1><<<dim3(4, 64), 256, 0, stream>>>(
        nullptr, nullptr, nullptr, chi, clo, wth, wtl, bo, nullptr, nullptr,
        outp, nullptr, nullptr, nullptr);
}

// Round 13
// 230.728 us; speedup vs baseline: 1.3194x; 1.0598x over previous
//
#include <hip/hip_runtime.h>
#include <hip/hip_bf16.h>

#define BB 8
#define SS 1024
#define DM 512
#define HH 8
#define BM 128
#define BN 128
#define BK 32
#define LD 40   // LDS row stride (bf16 elems): 80 B = 16B-aligned, 2-way banks

typedef __bf16 bf16x8 __attribute__((ext_vector_type(8)));
typedef __bf16 bf16x4 __attribute__((ext_vector_type(4)));
typedef float f32x4 __attribute__((ext_vector_type(4)));

__device__ __forceinline__ f32x4 mfma16(bf16x8 a, bf16x8 b, f32x4 c) {
    return __builtin_amdgcn_mfma_f32_16x16x32_bf16(a, b, c, 0, 0, 0);
}

// ---------------- W transpose + hi/lo split ----------------
__global__ __launch_bounds__(256) void wconv(
    const float* __restrict__ W0, const float* __restrict__ W1,
    const float* __restrict__ W2, const float* __restrict__ W3,
    __bf16* __restrict__ th, __bf16* __restrict__ tl)
{
    const float* W = blockIdx.z == 0 ? W0 : blockIdx.z == 1 ? W1
                   : blockIdx.z == 2 ? W2 : W3;
    __bf16* oh = th + (size_t)blockIdx.z * 512 * 512;
    __bf16* ol = tl + (size_t)blockIdx.z * 512 * 512;
    __shared__ float T[64][65];
    const int k0 = blockIdx.x * 64, n0 = blockIdx.y * 64;
    const int r = threadIdx.x >> 4, c4 = (threadIdx.x & 15) * 4;
    #pragma unroll
    for (int p = 0; p < 4; ++p) {
        float4 v = *(const float4*)(W + (size_t)(k0 + p * 16 + r) * 512 + n0 + c4);
        T[p * 16 + r][c4 + 0] = v.x; T[p * 16 + r][c4 + 1] = v.y;
        T[p * 16 + r][c4 + 2] = v.z; T[p * 16 + r][c4 + 3] = v.w;
    }
    __syncthreads();
    #pragma unroll
    for (int p = 0; p < 4; ++p) {
        int n = n0 + p * 16 + r;
        bf16x4 h4, l4;
        #pragma unroll
        for (int j = 0; j < 4; ++j) {
            float x = T[c4 + j][p * 16 + r];
            __bf16 h = (__bf16)x;
            h4[j] = h; l4[j] = (__bf16)(x - (float)h);
        }
        *(bf16x4*)(oh + (size_t)n * 512 + k0 + c4) = h4;
        *(bf16x4*)(ol + (size_t)n * 512 + k0 + c4) = l4;
    }
}

// ---------------- LDS-staged tile GEMM ----------------
template<int MODE>
__global__ __launch_bounds__(256, 3) void gemm_tile(
    const float* __restrict__ Aq, const float* __restrict__ Ak,
    const float* __restrict__ Av,
    const __bf16* __restrict__ Ahig, const __bf16* __restrict__ Alog,
    const __bf16* __restrict__ Wth, const __bf16* __restrict__ Wtl,
    const float* __restrict__ bq, const float* __restrict__ bk,
    const float* __restrict__ bv,
    float* __restrict__ Cf, __bf16* __restrict__ qo, __bf16* __restrict__ ko,
    __bf16* __restrict__ vo)
{
    __shared__ __align__(16) __bf16 Ah[BM][LD];
    __shared__ __align__(16) __bf16 Al[(MODE == 1 ? BM : 1)][LD];
    __shared__ __align__(16) __bf16 Bh[BN][LD];
    __shared__ __align__(16) __bf16 Bl[BN][LD];

    const int tid = threadIdx.x;
    const int w = tid >> 6, lane = tid & 63, l15 = lane & 15, lg = lane >> 4;
    const int wm = w >> 1, wn = w & 1;
    const int bx = blockIdx.x;
    const int z  = MODE == 0 ? (bx >> 2) : 3;
    const int n0 = MODE == 0 ? (bx & 3) * BN : bx * BN;
    const int m0 = blockIdx.y * BM;

    const float* Afp = (MODE == 0) ? (z == 0 ? Aq : z == 1 ? Ak : Av) : nullptr;
    const __bf16* wh = Wth + (size_t)z * 512 * 512;
    const __bf16* wl = Wtl + (size_t)z * 512 * 512;

    f32x4 acc[4][4];
    #pragma unroll
    for (int i = 0; i < 4; ++i)
        #pragma unroll
        for (int j = 0; j < 4; ++j) acc[i][j] = (f32x4){0.f, 0.f, 0.f, 0.f};

    for (int k0 = 0; k0 < 512; k0 += BK) {
        __syncthreads();
        if (MODE == 0) {
            const int row = tid >> 3, c = (tid & 7) * 4;
            #pragma unroll
            for (int p = 0; p < 4; ++p) {
                int rr = row + p * 32;
                f32x4 a = *(const f32x4*)(Afp + (size_t)(m0 + rr) * 512 + k0 + c);
                bf16x4 h4;
                #pragma unroll
                for (int j = 0; j < 4; ++j) h4[j] = (__bf16)a[j];
                *(bf16x4*)&Ah[rr][c] = h4;
            }
        } else {
            const int row = tid >> 2, c = (tid & 3) * 8;
            #pragma unroll
            for (int p = 0; p < 2; ++p) {
                int rr = row + p * 64;
                *(bf16x8*)&Ah[rr][c] =
                    *(const bf16x8*)(Ahig + (size_t)(m0 + rr) * 512 + k0 + c);
                *(bf16x8*)&Al[rr][c] =
                    *(const bf16x8*)(Alog + (size_t)(m0 + rr) * 512 + k0 + c);
            }
        }
        {
            const int row = tid >> 2, c = (tid & 3) * 8;
            #pragma unroll
            for (int p = 0; p < 2; ++p) {
                int rr = row + p * 64;
                *(bf16x8*)&Bh[rr][c] =
                    *(const bf16x8*)(wh + (size_t)(n0 + rr) * 512 + k0 + c);
                *(bf16x8*)&Bl[rr][c] =
                    *(const bf16x8*)(wl + (size_t)(n0 + rr) * 512 + k0 + c);
            }
        }
        __syncthreads();

        bf16x8 afh[4], afl[4];
        #pragma unroll
        for (int mt = 0; mt < 4; ++mt) {
            afh[mt] = *(const bf16x8*)&Ah[wm * 64 + mt * 16 + l15][lg * 8];
            if (MODE == 1)
                afl[mt] = *(const bf16x8*)&Al[wm * 64 + mt * 16 + l15][lg * 8];
        }
        #pragma unroll
        for (int nt = 0; nt < 4; ++nt) {
            bf16x8 bfh = *(const bf16x8*)&Bh[wn * 64 + nt * 16 + l15][lg * 8];
            bf16x8 bfl = *(const bf16x8*)&Bl[wn * 64 + nt * 16 + l15][lg * 8];
            #pragma unroll
            for (int mt = 0; mt < 4; ++mt) {
                acc[mt][nt] = mfma16(afh[mt], bfh, acc[mt][nt]);
                acc[mt][nt] = mfma16(afh[mt], bfl, acc[mt][nt]);
                if (MODE == 1)
                    acc[mt][nt] = mfma16(afl[mt], bfh, acc[mt][nt]);
            }
        }
    }

    const float* bias = (MODE == 1) ? bq : (z == 0 ? bq : z == 1 ? bk : bv);
    #pragma unroll
    for (int nt = 0; nt < 4; ++nt) {
        const int n = n0 + wn * 64 + nt * 16 + l15;
        const float bz = bias[n];
        #pragma unroll
        for (int mt = 0; mt < 4; ++mt) {
            if (MODE == 0 && z == 2) {
                bf16x4 v4;
                int mbase = m0 + wm * 64 + mt * 16 + lg * 4;
                #pragma unroll
                for (int rr = 0; rr < 4; ++rr)
                    v4[rr] = (__bf16)(acc[mt][nt][rr] + bz);
                int bb = mbase >> 10, s = mbase & 1023, h = n >> 6, d = n & 63;
                *(bf16x4*)(vo + ((size_t)(bb * HH + h) * 64 + d) * SS + s) = v4;
            } else {
                #pragma unroll
                for (int rr = 0; rr < 4; ++rr) {
                    int m = m0 + wm * 64 + mt * 16 + lg * 4 + rr;
                    float v = acc[mt][nt][rr] + bz;
                    if (MODE == 1) {
                        Cf[(size_t)m * 512 + n] = v;
                    } else {
                        int bb = m >> 10, s = m & 1023, h = n >> 6, d = n & 63;
                        __bf16* outp = z == 0 ? qo : ko;
                        outp[((size_t)(bb * HH + h) * SS + s) * 64 + d] = (__bf16)v;
                    }
                }
            }
        }
    }
}

// ---------------- G precompute ----------------
__global__ __launch_bounds__(256) void gprep(
    const float* __restrict__ mask, const float* __restrict__ adj,
    const float* __restrict__ dist,
    __bf16* __restrict__ Gg, float* __restrict__ rowILg)
{
    const int w = threadIdx.x >> 6, lane = threadIdx.x & 63;
    const int row = blockIdx.x * 4 + w;
    const int b = row >> 10;
    const size_t drow = (size_t)row * SS;
    const float L2E = 1.44269504f;
    const float* mrow = mask + (size_t)b * SS;
    float sm = 0.f;
    #pragma unroll
    for (int j = 0; j < 4; ++j) {
        int c = lane * 4 + j * 256;
        f32x4 d4 = *(const f32x4*)(dist + drow + c);
        f32x4 a4 = *(const f32x4*)(adj + drow + c);
        f32x4 m4 = *(const f32x4*)(mrow + c);
        bf16x4 g4;
        #pragma unroll
        for (int r = 0; r < 4; ++r) {
            float e = exp2f(fmaf(m4[r], -1e9f * L2E, fmaf(d4[r], L2E, -L2E)));
            sm += e;
            g4[r] = (__bf16)(a4[r] * e);
        }
        *(bf16x4*)(Gg + drow + c) = g4;
    }
    #pragma unroll
    for (int off = 1; off <= 32; off <<= 1)
        sm += __shfl_xor(sm, off, 64);
    if (lane == 0) rowILg[row] = 1.0f / sm;
}

// ---------------- Fused attention v8: 32 q-rows/block, single pass ----------------
// grid 2048 flat: h = bid&7, b = (bid>>3)&7, qt = bid>>6 (32 rows each).
// 512 thr = 8 waves. Pass1: wave w -> keys [128w,+128) x all 32 q.
// PV: wave (qh=w>>2, dh=w&3) -> q-rows [16qh,+16), d-cols [16dh,+16).
// K,V,G read ONCE per block (vs per-16q-tile) -> ~40% less L2/L3 fabric traffic.
__global__ __launch_bounds__(512, 4) void attn8(
    const __bf16* __restrict__ qh_, const __bf16* __restrict__ kh,
    const __bf16* __restrict__ vt,
    const float* __restrict__ mask, const __bf16* __restrict__ Gg,
    const float* __restrict__ rowILg,
    float* __restrict__ attn_out, __bf16* __restrict__ chi, __bf16* __restrict__ clo)
{
    __shared__ float nmb[1024];
    __shared__ __align__(16) __bf16 P[32][1024];   // XOR-swizzled: byte ^= (row&7)<<4
    __shared__ float redl[8][32];

    const int tid = threadIdx.x;
    const int w = tid >> 6, lane = tid & 63, l15 = lane & 15, lg = lane >> 4;
    const int bid = blockIdx.x;
    const int h = bid & 7;
    const int b = (bid >> 3) & 7;
    const int q0 = (bid >> 6) * 32;
    const float L2E = 1.44269504f;
    const float c1 = 0.125f * L2E;

    char* Pb = (char*)P;
    #define PADDR(row, bytes) (Pb + (row) * 2048 + ((bytes) ^ (((row) & 7) << 4)))

    #pragma unroll
    for (int i = 0; i < 2; ++i) {
        int c = tid + 512 * i;
        nmb[c] = fmaf(mask[(size_t)b * SS + c], -1e9f * L2E, -16.0f * L2E);
    }
    __syncthreads();

    const size_t hb = ((size_t)(b * HH + h)) * SS * 64;
    // Q fragments for both q-subtiles
    bf16x8 qf[2][2];
    #pragma unroll
    for (int qt = 0; qt < 2; ++qt)
        #pragma unroll
        for (int ks = 0; ks < 2; ++ks)
            qf[qt][ks] = *(const bf16x8*)(qh_ + hb
                + (size_t)(q0 + qt * 16 + l15) * 64 + ks * 32 + lg * 8);

    const __bf16* kp = kh + hb + (size_t)(w * 128 + l15) * 64 + lg * 8;
    const __bf16* gp0 = Gg + ((size_t)b * SS + q0 + l15) * SS;       // +qt*16*SS rows

    // ---- pass 1: QK^T, wave w covers keys [128w, 128w+128) for all 32 q ----
    float lac[2] = {0.f, 0.f};
    #pragma unroll
    for (int kt = 0; kt < 8; ++kt) {
        const int KT = w * 8 + kt;                   // global key-tile
        bf16x8 k0v = *(const bf16x8*)(kp + (size_t)kt * 1024);
        bf16x8 k1v = *(const bf16x8*)(kp + (size_t)kt * 1024 + 32);
        f32x4 nb4 = *(const f32x4*)&nmb[KT * 16 + lg * 4];
        #pragma unroll
        for (int qt = 0; qt < 2; ++qt) {
            f32x4 acc = {0.f, 0.f, 0.f, 0.f};
            acc = mfma16(k0v, qf[qt][0], acc);
            acc = mfma16(k1v, qf[qt][1], acc);
            bf16x4 g4 = *(const bf16x4*)(gp0 + (size_t)qt * 16 * SS + KT * 16 + lg * 4);
            float e0 = exp2f(fmaf(acc[0], c1, nb4[0]));
            float e1 = exp2f(fmaf(acc[1], c1, nb4[1]));
            float e2 = exp2f(fmaf(acc[2], c1, nb4[2]));
            float e3 = exp2f(fmaf(acc[3], c1, nb4[3]));
            lac[qt] += (e0 + e1) + (e2 + e3);
            bf16x4 pb;
            pb[0] = (__bf16)(e0 * (float)g4[0]);
            pb[1] = (__bf16)(e1 * (float)g4[1]);
            pb[2] = (__bf16)(e2 * (float)g4[2]);
            pb[3] = (__bf16)(e3 * (float)g4[3]);
            *(bf16x4*)PADDR(qt * 16 + l15, KT * 32 + lg * 8) = pb;
        }
    }
    #pragma unroll
    for (int qt = 0; qt < 2; ++qt) {
        float l = lac[qt];
        #pragma unroll
        for (int off = 16; off <= 32; off <<= 1)
            l += __shfl_xor(l, off, 64);
        if (lg == 0) redl[w][qt * 16 + l15] = l;
    }
    __syncthreads();

    // ---- attn write: wave w -> q-rows [4w, 4w+4) ----
    const float* rg = rowILg + (size_t)b * SS + q0;
    float* aoutb = attn_out + ((size_t)(b * HH + h)) * SS * SS;
    #pragma unroll
    for (int r = 0; r < 4; ++r) {
        const int row = w * 4 + r;
        float ltot = 0.f;
        #pragma unroll
        for (int w2 = 0; w2 < 8; ++w2) ltot += redl[w2][row];
        const float coefR = rg[row] / ltot;
        float* ar = aoutb + (size_t)(q0 + row) * SS;
        #pragma unroll
        for (int j = 0; j < 4; ++j) {
            const int bytes = lane * 8 + j * 512;
            bf16x4 pb = *(const bf16x4*)PADDR(row, bytes);
            f32x4 av;
            #pragma unroll
            for (int r2 = 0; r2 < 4; ++r2) av[r2] = (float)pb[r2] * coefR;
            __builtin_nontemporal_store(av, (f32x4*)(ar + (bytes >> 1)));
        }
    }

    // ---- PV: wave (qh, dh): q-rows [16qh,+16), d-cols [16dh,+16), all keys ----
    const int qhw = w >> 2, dhw = w & 3;
    f32x4 cacc = {0.f, 0.f, 0.f, 0.f};
    const __bf16* vb = vt + ((size_t)(b * HH + h) * 64 + dhw * 16 + l15) * SS + lg * 8;
    #pragma unroll 8
    for (int c = 0; c < 32; ++c) {
        bf16x8 pa = *(const bf16x8*)PADDR(qhw * 16 + l15, c * 64 + lg * 16);
        bf16x8 vv = *(const bf16x8*)(vb + c * 32);
        cacc = mfma16(pa, vv, cacc);
    }

    // ---- epilogue: normalize, write ctx hi/lo ----
    #pragma unroll
    for (int r = 0; r < 4; ++r) {
        const int row = qhw * 16 + lg * 4 + r;
        float ltot = 0.f;
        #pragma unroll
        for (int w2 = 0; w2 < 8; ++w2) ltot += redl[w2][row];
        const float coefE = rg[row] / ltot;
        float x = cacc[r] * coefE;
        __bf16 hv = (__bf16)x;
        size_t idx = ((size_t)b * SS + q0 + row) * DM + h * 64 + dhw * 16 + l15;
        chi[idx] = hv;
        clo[idx] = (__bf16)(x - (float)hv);
    }
    #undef PADDR
}

extern "C" void kernel_launch(void* const* d_in, const int* in_sizes, int n_in,
                              void* d_out, int out_size, void* d_ws, size_t ws_size,
                              hipStream_t stream) {
    const float* q    = (const float*)d_in[0];
    const float* k    = (const float*)d_in[1];
    const float* v    = (const float*)d_in[2];
    const float* mask = (const float*)d_in[3];
    const float* adj  = (const float*)d_in[4];
    const float* dist = (const float*)d_in[5];
    const float* Wq   = (const float*)d_in[6];
    const float* bq   = (const float*)d_in[7];
    const float* Wk   = (const float*)d_in[8];
    const float* bk   = (const float*)d_in[9];
    const float* Wv   = (const float*)d_in[10];
    const float* bv   = (const float*)d_in[11];
    const float* Wo   = (const float*)d_in[12];
    const float* bo   = (const float*)d_in[13];

    const size_t NT = (size_t)BB * SS * DM;   // 4,194,304
    const size_t WN = 512 * 512;
    const size_t NSS = (size_t)BB * SS * SS;  // 8,388,608
    __bf16* wth = (__bf16*)d_ws;
    __bf16* wtl = wth + 4 * WN;
    __bf16* qhb = wtl + 4 * WN;
    __bf16* khb = qhb + NT;
    __bf16* vtb = khb + NT;
    __bf16* chi = vtb + NT;
    __bf16* clo = chi + NT;
    __bf16* Gg  = clo + NT;
    float* rowILg = (float*)(Gg + NSS);

    float* outp = (float*)d_out;
    float* attn = outp + NT;

    wconv<<<dim3(8, 8, 4), 256, 0, stream>>>(Wq, Wk, Wv, Wo, wth, wtl);

    gprep<<<2048, 256, 0, stream>>>(mask, adj, dist, Gg, rowILg);

    gemm_tile<0><<<dim3(12, 64), 256, 0, stream>>>(
        q, k, v, nullptr, nullptr, wth, wtl, bq, bk, bv,
        nullptr, qhb, khb, vtb);

    attn8<<<2048, 512, 0, stream>>>(qhb, khb, vtb, mask, Gg, rowILg, attn, chi, clo);

    gemm_tile<1><<<dim3(4, 64), 256, 0, stream>>>(
        nullptr, nullptr, nullptr, chi, clo, wth, wtl, bo, nullptr, nullptr,
        outp, nullptr, nullptr, nullptr);
}

// Round 14
// 212.865 us; speedup vs baseline: 1.4302x; 1.0839x over previous
//
#include <hip/hip_runtime.h>
#include <hip/hip_bf16.h>

#define BB 8
#define SS 1024
#define DM 512
#define HH 8
#define BM 128
#define BN 128
#define BK 32
#define LD 40   // LDS row stride (bf16 elems): 80 B = 16B-aligned, 2-way banks

typedef __bf16 bf16x8 __attribute__((ext_vector_type(8)));
typedef __bf16 bf16x4 __attribute__((ext_vector_type(4)));
typedef float f32x4 __attribute__((ext_vector_type(4)));

__device__ __forceinline__ f32x4 mfma16(bf16x8 a, bf16x8 b, f32x4 c) {
    return __builtin_amdgcn_mfma_f32_16x16x32_bf16(a, b, c, 0, 0, 0);
}

// ---------------- W transpose + hi/lo split ----------------
__global__ __launch_bounds__(256) void wconv(
    const float* __restrict__ W0, const float* __restrict__ W1,
    const float* __restrict__ W2, const float* __restrict__ W3,
    __bf16* __restrict__ th, __bf16* __restrict__ tl)
{
    const float* W = blockIdx.z == 0 ? W0 : blockIdx.z == 1 ? W1
                   : blockIdx.z == 2 ? W2 : W3;
    __bf16* oh = th + (size_t)blockIdx.z * 512 * 512;
    __bf16* ol = tl + (size_t)blockIdx.z * 512 * 512;
    __shared__ float T[64][65];
    const int k0 = blockIdx.x * 64, n0 = blockIdx.y * 64;
    const int r = threadIdx.x >> 4, c4 = (threadIdx.x & 15) * 4;
    #pragma unroll
    for (int p = 0; p < 4; ++p) {
        float4 v = *(const float4*)(W + (size_t)(k0 + p * 16 + r) * 512 + n0 + c4);
        T[p * 16 + r][c4 + 0] = v.x; T[p * 16 + r][c4 + 1] = v.y;
        T[p * 16 + r][c4 + 2] = v.z; T[p * 16 + r][c4 + 3] = v.w;
    }
    __syncthreads();
    #pragma unroll
    for (int p = 0; p < 4; ++p) {
        int n = n0 + p * 16 + r;
        bf16x4 h4, l4;
        #pragma unroll
        for (int j = 0; j < 4; ++j) {
            float x = T[c4 + j][p * 16 + r];
            __bf16 h = (__bf16)x;
            h4[j] = h; l4[j] = (__bf16)(x - (float)h);
        }
        *(bf16x4*)(oh + (size_t)n * 512 + k0 + c4) = h4;
        *(bf16x4*)(ol + (size_t)n * 512 + k0 + c4) = l4;
    }
}

// ---------------- LDS-staged tile GEMM ----------------
template<int MODE>
__global__ __launch_bounds__(256, 3) void gemm_tile(
    const float* __restrict__ Aq, const float* __restrict__ Ak,
    const float* __restrict__ Av,
    const __bf16* __restrict__ Ahig, const __bf16* __restrict__ Alog,
    const __bf16* __restrict__ Wth, const __bf16* __restrict__ Wtl,
    const float* __restrict__ bq, const float* __restrict__ bk,
    const float* __restrict__ bv,
    float* __restrict__ Cf, __bf16* __restrict__ qo, __bf16* __restrict__ ko,
    __bf16* __restrict__ vo)
{
    __shared__ __align__(16) __bf16 Ah[BM][LD];
    __shared__ __align__(16) __bf16 Al[(MODE == 1 ? BM : 1)][LD];
    __shared__ __align__(16) __bf16 Bh[BN][LD];
    __shared__ __align__(16) __bf16 Bl[BN][LD];

    const int tid = threadIdx.x;
    const int w = tid >> 6, lane = tid & 63, l15 = lane & 15, lg = lane >> 4;
    const int wm = w >> 1, wn = w & 1;
    const int bx = blockIdx.x;
    const int z  = MODE == 0 ? (bx >> 2) : 3;
    const int n0 = MODE == 0 ? (bx & 3) * BN : bx * BN;
    const int m0 = blockIdx.y * BM;

    const float* Afp = (MODE == 0) ? (z == 0 ? Aq : z == 1 ? Ak : Av) : nullptr;
    const __bf16* wh = Wth + (size_t)z * 512 * 512;
    const __bf16* wl = Wtl + (size_t)z * 512 * 512;

    f32x4 acc[4][4];
    #pragma unroll
    for (int i = 0; i < 4; ++i)
        #pragma unroll
        for (int j = 0; j < 4; ++j) acc[i][j] = (f32x4){0.f, 0.f, 0.f, 0.f};

    for (int k0 = 0; k0 < 512; k0 += BK) {
        __syncthreads();
        if (MODE == 0) {
            const int row = tid >> 3, c = (tid & 7) * 4;
            #pragma unroll
            for (int p = 0; p < 4; ++p) {
                int rr = row + p * 32;
                f32x4 a = *(const f32x4*)(Afp + (size_t)(m0 + rr) * 512 + k0 + c);
                bf16x4 h4;
                #pragma unroll
                for (int j = 0; j < 4; ++j) h4[j] = (__bf16)a[j];
                *(bf16x4*)&Ah[rr][c] = h4;
            }
        } else {
            const int row = tid >> 2, c = (tid & 3) * 8;
            #pragma unroll
            for (int p = 0; p < 2; ++p) {
                int rr = row + p * 64;
                *(bf16x8*)&Ah[rr][c] =
                    *(const bf16x8*)(Ahig + (size_t)(m0 + rr) * 512 + k0 + c);
                *(bf16x8*)&Al[rr][c] =
                    *(const bf16x8*)(Alog + (size_t)(m0 + rr) * 512 + k0 + c);
            }
        }
        {
            const int row = tid >> 2, c = (tid & 3) * 8;
            #pragma unroll
            for (int p = 0; p < 2; ++p) {
                int rr = row + p * 64;
                *(bf16x8*)&Bh[rr][c] =
                    *(const bf16x8*)(wh + (size_t)(n0 + rr) * 512 + k0 + c);
                *(bf16x8*)&Bl[rr][c] =
                    *(const bf16x8*)(wl + (size_t)(n0 + rr) * 512 + k0 + c);
            }
        }
        __syncthreads();

        bf16x8 afh[4], afl[4];
        #pragma unroll
        for (int mt = 0; mt < 4; ++mt) {
            afh[mt] = *(const bf16x8*)&Ah[wm * 64 + mt * 16 + l15][lg * 8];
            if (MODE == 1)
                afl[mt] = *(const bf16x8*)&Al[wm * 64 + mt * 16 + l15][lg * 8];
        }
        #pragma unroll
        for (int nt = 0; nt < 4; ++nt) {
            bf16x8 bfh = *(const bf16x8*)&Bh[wn * 64 + nt * 16 + l15][lg * 8];
            bf16x8 bfl = *(const bf16x8*)&Bl[wn * 64 + nt * 16 + l15][lg * 8];
            #pragma unroll
            for (int mt = 0; mt < 4; ++mt) {
                acc[mt][nt] = mfma16(afh[mt], bfh, acc[mt][nt]);
                acc[mt][nt] = mfma16(afh[mt], bfl, acc[mt][nt]);
                if (MODE == 1)
                    acc[mt][nt] = mfma16(afl[mt], bfh, acc[mt][nt]);
            }
        }
    }

    const float* bias = (MODE == 1) ? bq : (z == 0 ? bq : z == 1 ? bk : bv);
    #pragma unroll
    for (int nt = 0; nt < 4; ++nt) {
        const int n = n0 + wn * 64 + nt * 16 + l15;
        const float bz = bias[n];
        #pragma unroll
        for (int mt = 0; mt < 4; ++mt) {
            if (MODE == 0 && z == 2) {
                bf16x4 v4;
                int mbase = m0 + wm * 64 + mt * 16 + lg * 4;
                #pragma unroll
                for (int rr = 0; rr < 4; ++rr)
                    v4[rr] = (__bf16)(acc[mt][nt][rr] + bz);
                int bb = mbase >> 10, s = mbase & 1023, h = n >> 6, d = n & 63;
                *(bf16x4*)(vo + ((size_t)(bb * HH + h) * 64 + d) * SS + s) = v4;
            } else {
                #pragma unroll
                for (int rr = 0; rr < 4; ++rr) {
                    int m = m0 + wm * 64 + mt * 16 + lg * 4 + rr;
                    float v = acc[mt][nt][rr] + bz;
                    if (MODE == 1) {
                        Cf[(size_t)m * 512 + n] = v;
                    } else {
                        int bb = m >> 10, s = m & 1023, h = n >> 6, d = n & 63;
                        __bf16* outp = z == 0 ? qo : ko;
                        outp[((size_t)(bb * HH + h) * SS + s) * 64 + d] = (__bf16)v;
                    }
                }
            }
        }
    }
}

// ---------------- G precompute ----------------
__global__ __launch_bounds__(256) void gprep(
    const float* __restrict__ mask, const float* __restrict__ adj,
    const float* __restrict__ dist,
    __bf16* __restrict__ Gg, float* __restrict__ rowILg)
{
    const int w = threadIdx.x >> 6, lane = threadIdx.x & 63;
    const int row = blockIdx.x * 4 + w;
    const int b = row >> 10;
    const size_t drow = (size_t)row * SS;
    const float L2E = 1.44269504f;
    const float* mrow = mask + (size_t)b * SS;
    float sm = 0.f;
    #pragma unroll
    for (int j = 0; j < 4; ++j) {
        int c = lane * 4 + j * 256;
        f32x4 d4 = *(const f32x4*)(dist + drow + c);
        f32x4 a4 = *(const f32x4*)(adj + drow + c);
        f32x4 m4 = *(const f32x4*)(mrow + c);
        bf16x4 g4;
        #pragma unroll
        for (int r = 0; r < 4; ++r) {
            float e = exp2f(fmaf(m4[r], -1e9f * L2E, fmaf(d4[r], L2E, -L2E)));
            sm += e;
            g4[r] = (__bf16)(a4[r] * e);
        }
        *(bf16x4*)(Gg + drow + c) = g4;
    }
    #pragma unroll
    for (int off = 1; off <= 32; off <<= 1)
        sm += __shfl_xor(sm, off, 64);
    if (lane == 0) rowILg[row] = 1.0f / sm;
}

// ---------------- Fused attention v9: LDS-staged K/V, coalesced G ----------------
// grid 2048: h = bid&7, b = (bid>>3)&7, qt = bid>>6 (32 q-rows). 512 thr = 8 waves.
// 16 chunks x 64 keys. Pass1: stage K chunk coalesced -> LDS, wave (qsub=w>>2,
// kt=w&3) computes E -> P (ungated bf16, swizzled). Gate phase: G read
// row-coalesced, attn written, gated P written back. PV: stage V chunks, MFMA
// from LDS. All LDS fragment reads XOR-swizzled (byte ^= (row&7)<<4).
__global__ __launch_bounds__(512, 4) void attn9(
    const __bf16* __restrict__ qh_, const __bf16* __restrict__ kh,
    const __bf16* __restrict__ vt,
    const float* __restrict__ mask, const __bf16* __restrict__ Gg,
    const float* __restrict__ rowILg,
    float* __restrict__ attn_out, __bf16* __restrict__ chi, __bf16* __restrict__ clo)
{
    __shared__ float nmb[1024];                        // 4 KB
    __shared__ __align__(16) __bf16 P[32][1024];       // 64 KB, swizzled
    __shared__ __align__(16) __bf16 KV[64][64];        // 8 KB chunk buffer, swizzled
    __shared__ float redl[8][16];

    const int tid = threadIdx.x;
    const int w = tid >> 6, lane = tid & 63, l15 = lane & 15, lg = lane >> 4;
    const int bid = blockIdx.x;
    const int h = bid & 7;
    const int b = (bid >> 3) & 7;
    const int q0 = (bid >> 6) * 32;
    const float L2E = 1.44269504f;
    const float c1 = 0.125f * L2E;

    char* Pb = (char*)P;
    char* KVb = (char*)KV;
    const int srow = tid >> 3;               // staging row (64 rows, 8 thr/row)
    const int scol = (tid & 7) * 8;          // staging elem offset within row

    #pragma unroll
    for (int i = 0; i < 2; ++i) {
        int c = tid + 512 * i;
        nmb[c] = fmaf(mask[(size_t)b * SS + c], -1e9f * L2E, -16.0f * L2E);
    }

    const size_t hb = ((size_t)(b * HH + h)) * SS * 64;
    const int qsub = w >> 2, ktw = w & 3;
    bf16x8 qf0 = *(const bf16x8*)(qh_ + hb + (size_t)(q0 + qsub * 16 + l15) * 64 + lg * 8);
    bf16x8 qf1 = *(const bf16x8*)(qh_ + hb + (size_t)(q0 + qsub * 16 + l15) * 64 + 32 + lg * 8);

    const int krow = ktw * 16 + l15;                       // K fragment row in chunk
    const int kswz = (krow & 7) << 4;
    const int prow = qsub * 16 + l15;                      // P row (q)
    const int pswz = (prow & 7) << 4;

    // ---- pass 1: 16 chunks of 64 keys ----
    float lac = 0.f;
    for (int c = 0; c < 16; ++c) {
        __syncthreads();                                   // KV free to overwrite
        {
            bf16x8 kv = *(const bf16x8*)(kh + hb + (size_t)(c * 64 + srow) * 64 + scol);
            *(bf16x8*)(KVb + srow * 128 + ((scol * 2) ^ ((srow & 7) << 4))) = kv;
        }
        __syncthreads();
        bf16x8 k0v = *(const bf16x8*)(KVb + krow * 128 + ((lg * 16) ^ kswz));
        bf16x8 k1v = *(const bf16x8*)(KVb + krow * 128 + ((64 + lg * 16) ^ kswz));
        f32x4 acc = {0.f, 0.f, 0.f, 0.f};
        acc = mfma16(k0v, qf0, acc);
        acc = mfma16(k1v, qf1, acc);
        const int key4 = c * 64 + ktw * 16 + lg * 4;
        f32x4 nb4 = *(const f32x4*)&nmb[key4];
        float e0 = exp2f(fmaf(acc[0], c1, nb4[0]));
        float e1 = exp2f(fmaf(acc[1], c1, nb4[1]));
        float e2 = exp2f(fmaf(acc[2], c1, nb4[2]));
        float e3 = exp2f(fmaf(acc[3], c1, nb4[3]));
        lac += (e0 + e1) + (e2 + e3);
        bf16x4 pb;
        pb[0] = (__bf16)e0; pb[1] = (__bf16)e1;
        pb[2] = (__bf16)e2; pb[3] = (__bf16)e3;
        *(bf16x4*)(Pb + prow * 2048 + ((key4 * 2) ^ pswz)) = pb;
    }
    #pragma unroll
    for (int off = 16; off <= 32; off <<= 1)
        lac += __shfl_xor(lac, off, 64);
    if (lg == 0) redl[w][l15] = lac;
    __syncthreads();

    // ---- gate phase: wave w -> q-rows [4w, 4w+4); G coalesced; fold coef ----
    const float* rg = rowILg + (size_t)b * SS + q0;
    float* aoutb = attn_out + ((size_t)(b * HH + h)) * SS * SS;
    const __bf16* gb = Gg + ((size_t)b * SS + q0) * SS;
    #pragma unroll
    for (int r = 0; r < 4; ++r) {
        const int row = w * 4 + r;
        const int rs = (row >> 4) * 4;
        const float ltot = redl[rs][row & 15] + redl[rs + 1][row & 15]
                         + redl[rs + 2][row & 15] + redl[rs + 3][row & 15];
        const float coefR = rg[row] / ltot;
        const int rswz = (row & 7) << 4;
        float* ar = aoutb + (size_t)(q0 + row) * SS;
        const __bf16* gr = gb + (size_t)row * SS;
        #pragma unroll
        for (int j = 0; j < 4; ++j) {
            const int off = lane * 8 + j * 512;            // bytes within P row
            char* pp = Pb + row * 2048 + (off ^ rswz);
            bf16x4 e4 = *(const bf16x4*)pp;
            bf16x4 g4 = *(const bf16x4*)(gr + (off >> 1));
            f32x4 av;
            bf16x4 pb;
            #pragma unroll
            for (int r2 = 0; r2 < 4; ++r2) {
                float v = (float)e4[r2] * (float)g4[r2] * coefR;
                av[r2] = v;
                pb[r2] = (__bf16)v;
            }
            __builtin_nontemporal_store(av, (f32x4*)(ar + (off >> 1)));
            *(bf16x4*)pp = pb;
        }
    }

    // ---- PV: wave (qh = w>>2 .. wait 8 waves = 2q x 4d), stage V chunks ----
    const int dh = w & 3;
    const int vrow = dh * 16 + l15;
    const int vswz = (vrow & 7) << 4;
    f32x4 cacc = {0.f, 0.f, 0.f, 0.f};
    for (int c = 0; c < 16; ++c) {
        __syncthreads();                                   // KV / P(gated) ready
        {
            bf16x8 vv = *(const bf16x8*)(vt + ((size_t)(b * HH + h) * 64 + srow) * SS
                                         + c * 64 + scol);
            *(bf16x8*)(KVb + srow * 128 + ((scol * 2) ^ ((srow & 7) << 4))) = vv;
        }
        __syncthreads();
        #pragma unroll
        for (int ks = 0; ks < 2; ++ks) {
            bf16x8 pa = *(const bf16x8*)(Pb + prow * 2048
                          + ((c * 128 + ks * 64 + lg * 16) ^ pswz));
            bf16x8 vv = *(const bf16x8*)(KVb + vrow * 128 + ((ks * 64 + lg * 16) ^ vswz));
            cacc = mfma16(pa, vv, cacc);
        }
    }

    // ---- epilogue: coef already folded; write ctx hi/lo ----
    #pragma unroll
    for (int r = 0; r < 4; ++r) {
        const int row = qsub * 16 + lg * 4 + r;
        float x = cacc[r];
        __bf16 hv = (__bf16)x;
        size_t idx = ((size_t)b * SS + q0 + row) * DM + h * 64 + dh * 16 + l15;
        chi[idx] = hv;
        clo[idx] = (__bf16)(x - (float)hv);
    }
}

extern "C" void kernel_launch(void* const* d_in, const int* in_sizes, int n_in,
                              void* d_out, int out_size, void* d_ws, size_t ws_size,
                              hipStream_t stream) {
    const float* q    = (const float*)d_in[0];
    const float* k    = (const float*)d_in[1];
    const float* v    = (const float*)d_in[2];
    const float* mask = (const float*)d_in[3];
    const float* adj  = (const float*)d_in[4];
    const float* dist = (const float*)d_in[5];
    const float* Wq   = (const float*)d_in[6];
    const float* bq   = (const float*)d_in[7];
    const float* Wk   = (const float*)d_in[8];
    const float* bk   = (const float*)d_in[9];
    const float* Wv   = (const float*)d_in[10];
    const float* bv   = (const float*)d_in[11];
    const float* Wo   = (const float*)d_in[12];
    const float* bo   = (const float*)d_in[13];

    const size_t NT = (size_t)BB * SS * DM;   // 4,194,304
    const size_t WN = 512 * 512;
    const size_t NSS = (size_t)BB * SS * SS;  // 8,388,608
    __bf16* wth = (__bf16*)d_ws;
    __bf16* wtl = wth + 4 * WN;
    __bf16* qhb = wtl + 4 * WN;
    __bf16* khb = qhb + NT;
    __bf16* vtb = khb + NT;
    __bf16* chi = vtb + NT;
    __bf16* clo = chi + NT;
    __bf16* Gg  = clo + NT;
    float* rowILg = (float*)(Gg + NSS);

    float* outp = (float*)d_out;
    float* attn = outp + NT;

    wconv<<<dim3(8, 8, 4), 256, 0, stream>>>(Wq, Wk, Wv, Wo, wth, wtl);

    gprep<<<2048, 256, 0, stream>>>(mask, adj, dist, Gg, rowILg);

    gemm_tile<0><<<dim3(12, 64), 256, 0, stream>>>(
        q, k, v, nullptr, nullptr, wth, wtl, bq, bk, bv,
        nullptr, qhb, khb, vtb);

    attn9<<<2048, 512, 0, stream>>>(qhb, khb, vtb, mask, Gg, rowILg, attn, chi, clo);

    gemm_tile<1><<<dim3(4, 64), 256, 0, stream>>>(
        nullptr, nullptr, nullptr, chi, clo, wth, wtl, bo, nullptr, nullptr,
        outp, nullptr, nullptr, nullptr);
}

// Round 15
// 194.605 us; speedup vs baseline: 1.5643x; 1.0938x over previous
//
#include <hip/hip_runtime.h>
#include <hip/hip_bf16.h>

#define BB 8
#define SS 1024
#define DM 512
#define HH 8
#define BM 128
#define BN 128
#define BK 32
#define LD 40   // LDS row stride (bf16 elems): 80 B = 16B-aligned, 2-way banks

typedef __bf16 bf16x8 __attribute__((ext_vector_type(8)));
typedef __bf16 bf16x4 __attribute__((ext_vector_type(4)));
typedef float f32x4 __attribute__((ext_vector_type(4)));

__device__ __forceinline__ f32x4 mfma16(bf16x8 a, bf16x8 b, f32x4 c) {
    return __builtin_amdgcn_mfma_f32_16x16x32_bf16(a, b, c, 0, 0, 0);
}

// ---------------- W transpose + hi/lo split ----------------
__global__ __launch_bounds__(256) void wconv(
    const float* __restrict__ W0, const float* __restrict__ W1,
    const float* __restrict__ W2, const float* __restrict__ W3,
    __bf16* __restrict__ th, __bf16* __restrict__ tl)
{
    const float* W = blockIdx.z == 0 ? W0 : blockIdx.z == 1 ? W1
                   : blockIdx.z == 2 ? W2 : W3;
    __bf16* oh = th + (size_t)blockIdx.z * 512 * 512;
    __bf16* ol = tl + (size_t)blockIdx.z * 512 * 512;
    __shared__ float T[64][65];
    const int k0 = blockIdx.x * 64, n0 = blockIdx.y * 64;
    const int r = threadIdx.x >> 4, c4 = (threadIdx.x & 15) * 4;
    #pragma unroll
    for (int p = 0; p < 4; ++p) {
        float4 v = *(const float4*)(W + (size_t)(k0 + p * 16 + r) * 512 + n0 + c4);
        T[p * 16 + r][c4 + 0] = v.x; T[p * 16 + r][c4 + 1] = v.y;
        T[p * 16 + r][c4 + 2] = v.z; T[p * 16 + r][c4 + 3] = v.w;
    }
    __syncthreads();
    #pragma unroll
    for (int p = 0; p < 4; ++p) {
        int n = n0 + p * 16 + r;
        bf16x4 h4, l4;
        #pragma unroll
        for (int j = 0; j < 4; ++j) {
            float x = T[c4 + j][p * 16 + r];
            __bf16 h = (__bf16)x;
            h4[j] = h; l4[j] = (__bf16)(x - (float)h);
        }
        *(bf16x4*)(oh + (size_t)n * 512 + k0 + c4) = h4;
        *(bf16x4*)(ol + (size_t)n * 512 + k0 + c4) = l4;
    }
}

// ---------------- LDS-staged tile GEMM ----------------
template<int MODE>
__global__ __launch_bounds__(256, 3) void gemm_tile(
    const float* __restrict__ Aq, const float* __restrict__ Ak,
    const float* __restrict__ Av,
    const __bf16* __restrict__ Ahig, const __bf16* __restrict__ Alog,
    const __bf16* __restrict__ Wth, const __bf16* __restrict__ Wtl,
    const float* __restrict__ bq, const float* __restrict__ bk,
    const float* __restrict__ bv,
    float* __restrict__ Cf, __bf16* __restrict__ qo, __bf16* __restrict__ ko,
    __bf16* __restrict__ vo)
{
    __shared__ __align__(16) __bf16 Ah[BM][LD];
    __shared__ __align__(16) __bf16 Al[(MODE == 1 ? BM : 1)][LD];
    __shared__ __align__(16) __bf16 Bh[BN][LD];
    __shared__ __align__(16) __bf16 Bl[BN][LD];

    const int tid = threadIdx.x;
    const int w = tid >> 6, lane = tid & 63, l15 = lane & 15, lg = lane >> 4;
    const int wm = w >> 1, wn = w & 1;
    const int bx = blockIdx.x;
    const int z  = MODE == 0 ? (bx >> 2) : 3;
    const int n0 = MODE == 0 ? (bx & 3) * BN : bx * BN;
    const int m0 = blockIdx.y * BM;

    const float* Afp = (MODE == 0) ? (z == 0 ? Aq : z == 1 ? Ak : Av) : nullptr;
    const __bf16* wh = Wth + (size_t)z * 512 * 512;
    const __bf16* wl = Wtl + (size_t)z * 512 * 512;

    f32x4 acc[4][4];
    #pragma unroll
    for (int i = 0; i < 4; ++i)
        #pragma unroll
        for (int j = 0; j < 4; ++j) acc[i][j] = (f32x4){0.f, 0.f, 0.f, 0.f};

    for (int k0 = 0; k0 < 512; k0 += BK) {
        __syncthreads();
        if (MODE == 0) {
            const int row = tid >> 3, c = (tid & 7) * 4;
            #pragma unroll
            for (int p = 0; p < 4; ++p) {
                int rr = row + p * 32;
                f32x4 a = *(const f32x4*)(Afp + (size_t)(m0 + rr) * 512 + k0 + c);
                bf16x4 h4;
                #pragma unroll
                for (int j = 0; j < 4; ++j) h4[j] = (__bf16)a[j];
                *(bf16x4*)&Ah[rr][c] = h4;
            }
        } else {
            const int row = tid >> 2, c = (tid & 3) * 8;
            #pragma unroll
            for (int p = 0; p < 2; ++p) {
                int rr = row + p * 64;
                *(bf16x8*)&Ah[rr][c] =
                    *(const bf16x8*)(Ahig + (size_t)(m0 + rr) * 512 + k0 + c);
                *(bf16x8*)&Al[rr][c] =
                    *(const bf16x8*)(Alog + (size_t)(m0 + rr) * 512 + k0 + c);
            }
        }
        {
            const int row = tid >> 2, c = (tid & 3) * 8;
            #pragma unroll
            for (int p = 0; p < 2; ++p) {
                int rr = row + p * 64;
                *(bf16x8*)&Bh[rr][c] =
                    *(const bf16x8*)(wh + (size_t)(n0 + rr) * 512 + k0 + c);
                *(bf16x8*)&Bl[rr][c] =
                    *(const bf16x8*)(wl + (size_t)(n0 + rr) * 512 + k0 + c);
            }
        }
        __syncthreads();

        bf16x8 afh[4], afl[4];
        #pragma unroll
        for (int mt = 0; mt < 4; ++mt) {
            afh[mt] = *(const bf16x8*)&Ah[wm * 64 + mt * 16 + l15][lg * 8];
            if (MODE == 1)
                afl[mt] = *(const bf16x8*)&Al[wm * 64 + mt * 16 + l15][lg * 8];
        }
        #pragma unroll
        for (int nt = 0; nt < 4; ++nt) {
            bf16x8 bfh = *(const bf16x8*)&Bh[wn * 64 + nt * 16 + l15][lg * 8];
            bf16x8 bfl = *(const bf16x8*)&Bl[wn * 64 + nt * 16 + l15][lg * 8];
            #pragma unroll
            for (int mt = 0; mt < 4; ++mt) {
                acc[mt][nt] = mfma16(afh[mt], bfh, acc[mt][nt]);
                acc[mt][nt] = mfma16(afh[mt], bfl, acc[mt][nt]);
                if (MODE == 1)
                    acc[mt][nt] = mfma16(afl[mt], bfh, acc[mt][nt]);
            }
        }
    }

    const float* bias = (MODE == 1) ? bq : (z == 0 ? bq : z == 1 ? bk : bv);
    #pragma unroll
    for (int nt = 0; nt < 4; ++nt) {
        const int n = n0 + wn * 64 + nt * 16 + l15;
        const float bz = bias[n];
        #pragma unroll
        for (int mt = 0; mt < 4; ++mt) {
            if (MODE == 0 && z == 2) {
                bf16x4 v4;
                int mbase = m0 + wm * 64 + mt * 16 + lg * 4;
                #pragma unroll
                for (int rr = 0; rr < 4; ++rr)
                    v4[rr] = (__bf16)(acc[mt][nt][rr] + bz);
                int bb = mbase >> 10, s = mbase & 1023, h = n >> 6, d = n & 63;
                *(bf16x4*)(vo + ((size_t)(bb * HH + h) * 64 + d) * SS + s) = v4;
            } else {
                #pragma unroll
                for (int rr = 0; rr < 4; ++rr) {
                    int m = m0 + wm * 64 + mt * 16 + lg * 4 + rr;
                    float v = acc[mt][nt][rr] + bz;
                    if (MODE == 1) {
                        Cf[(size_t)m * 512 + n] = v;
                    } else {
                        int bb = m >> 10, s = m & 1023, h = n >> 6, d = n & 63;
                        __bf16* outp = z == 0 ? qo : ko;
                        outp[((size_t)(bb * HH + h) * SS + s) * 64 + d] = (__bf16)v;
                    }
                }
            }
        }
    }
}

// ---------------- G precompute ----------------
__global__ __launch_bounds__(256) void gprep(
    const float* __restrict__ mask, const float* __restrict__ adj,
    const float* __restrict__ dist,
    __bf16* __restrict__ Gg, float* __restrict__ rowILg)
{
    const int w = threadIdx.x >> 6, lane = threadIdx.x & 63;
    const int row = blockIdx.x * 4 + w;
    const int b = row >> 10;
    const size_t drow = (size_t)row * SS;
    const float L2E = 1.44269504f;
    const float* mrow = mask + (size_t)b * SS;
    float sm = 0.f;
    #pragma unroll
    for (int j = 0; j < 4; ++j) {
        int c = lane * 4 + j * 256;
        f32x4 d4 = *(const f32x4*)(dist + drow + c);
        f32x4 a4 = *(const f32x4*)(adj + drow + c);
        f32x4 m4 = *(const f32x4*)(mrow + c);
        bf16x4 g4;
        #pragma unroll
        for (int r = 0; r < 4; ++r) {
            float e = exp2f(fmaf(m4[r], -1e9f * L2E, fmaf(d4[r], L2E, -L2E)));
            sm += e;
            g4[r] = (__bf16)(a4[r] * e);
        }
        *(bf16x4*)(Gg + drow + c) = g4;
    }
    #pragma unroll
    for (int off = 1; off <= 32; off <<= 1)
        sm += __shfl_xor(sm, off, 64);
    if (lane == 0) rowILg[row] = 1.0f / sm;
}

// ---------------- Fused attention v10: staged + T14 issue-early/write-late ----------------
// Same as attn9 but the chunk staging is register-pipelined: load chunk c+1 is
// issued right after the "KV ready" barrier and consumed after the next
// "KV free" barrier, so global latency hides under chunk-c compute.
__global__ __launch_bounds__(512, 4) void attn10(
    const __bf16* __restrict__ qh_, const __bf16* __restrict__ kh,
    const __bf16* __restrict__ vt,
    const float* __restrict__ mask, const __bf16* __restrict__ Gg,
    const float* __restrict__ rowILg,
    float* __restrict__ attn_out, __bf16* __restrict__ chi, __bf16* __restrict__ clo)
{
    __shared__ float nmb[1024];                        // 4 KB
    __shared__ __align__(16) __bf16 P[32][1024];       // 64 KB, swizzled
    __shared__ __align__(16) __bf16 KV[64][64];        // 8 KB chunk buffer, swizzled
    __shared__ float redl[8][16];

    const int tid = threadIdx.x;
    const int w = tid >> 6, lane = tid & 63, l15 = lane & 15, lg = lane >> 4;
    const int bid = blockIdx.x;
    const int h = bid & 7;
    const int b = (bid >> 3) & 7;
    const int q0 = (bid >> 6) * 32;
    const float L2E = 1.44269504f;
    const float c1 = 0.125f * L2E;

    char* Pb = (char*)P;
    char* KVb = (char*)KV;
    const int srow = tid >> 3;               // staging row (64 rows, 8 thr/row)
    const int scol = (tid & 7) * 8;          // staging elem offset within row
    const int sdst = srow * 128 + ((scol * 2) ^ ((srow & 7) << 4));

    #pragma unroll
    for (int i = 0; i < 2; ++i) {
        int c = tid + 512 * i;
        nmb[c] = fmaf(mask[(size_t)b * SS + c], -1e9f * L2E, -16.0f * L2E);
    }

    const size_t hb = ((size_t)(b * HH + h)) * SS * 64;
    const int qsub = w >> 2, ktw = w & 3;
    bf16x8 qf0 = *(const bf16x8*)(qh_ + hb + (size_t)(q0 + qsub * 16 + l15) * 64 + lg * 8);
    bf16x8 qf1 = *(const bf16x8*)(qh_ + hb + (size_t)(q0 + qsub * 16 + l15) * 64 + 32 + lg * 8);

    const int krow = ktw * 16 + l15;                       // K fragment row in chunk
    const int kswz = (krow & 7) << 4;
    const int prow = qsub * 16 + l15;                      // P row (q)
    const int pswz = (prow & 7) << 4;

    // ---- pass 1: 16 chunks of 64 keys, register-pipelined staging ----
    const __bf16* kcp = kh + hb + (size_t)srow * 64 + scol;
    bf16x8 kvreg = *(const bf16x8*)kcp;                    // chunk 0
    float lac = 0.f;
    for (int c = 0; c < 16; ++c) {
        __syncthreads();                                   // KV free
        *(bf16x8*)(KVb + sdst) = kvreg;                    // write chunk c
        __syncthreads();                                   // KV ready
        if (c + 1 < 16)
            kvreg = *(const bf16x8*)(kcp + (size_t)(c + 1) * 4096);  // 64 rows x 64 elems
        bf16x8 k0v = *(const bf16x8*)(KVb + krow * 128 + ((lg * 16) ^ kswz));
        bf16x8 k1v = *(const bf16x8*)(KVb + krow * 128 + ((64 + lg * 16) ^ kswz));
        f32x4 acc = {0.f, 0.f, 0.f, 0.f};
        acc = mfma16(k0v, qf0, acc);
        acc = mfma16(k1v, qf1, acc);
        const int key4 = c * 64 + ktw * 16 + lg * 4;
        f32x4 nb4 = *(const f32x4*)&nmb[key4];
        float e0 = exp2f(fmaf(acc[0], c1, nb4[0]));
        float e1 = exp2f(fmaf(acc[1], c1, nb4[1]));
        float e2 = exp2f(fmaf(acc[2], c1, nb4[2]));
        float e3 = exp2f(fmaf(acc[3], c1, nb4[3]));
        lac += (e0 + e1) + (e2 + e3);
        bf16x4 pb;
        pb[0] = (__bf16)e0; pb[1] = (__bf16)e1;
        pb[2] = (__bf16)e2; pb[3] = (__bf16)e3;
        *(bf16x4*)(Pb + prow * 2048 + ((key4 * 2) ^ pswz)) = pb;
    }
    #pragma unroll
    for (int off = 16; off <= 32; off <<= 1)
        lac += __shfl_xor(lac, off, 64);
    if (lg == 0) redl[w][l15] = lac;
    __syncthreads();

    // ---- gate phase: wave w -> q-rows [4w, 4w+4); G coalesced; fold coef ----
    const float* rg = rowILg + (size_t)b * SS + q0;
    float* aoutb = attn_out + ((size_t)(b * HH + h)) * SS * SS;
    const __bf16* gb = Gg + ((size_t)b * SS + q0) * SS;
    #pragma unroll
    for (int r = 0; r < 4; ++r) {
        const int row = w * 4 + r;
        const int rs = (row >> 4) * 4;
        const float ltot = redl[rs][row & 15] + redl[rs + 1][row & 15]
                         + redl[rs + 2][row & 15] + redl[rs + 3][row & 15];
        const float coefR = rg[row] / ltot;
        const int rswz = (row & 7) << 4;
        float* ar = aoutb + (size_t)(q0 + row) * SS;
        const __bf16* gr = gb + (size_t)row * SS;
        #pragma unroll
        for (int j = 0; j < 4; ++j) {
            const int off = lane * 8 + j * 512;            // bytes within P row
            char* pp = Pb + row * 2048 + (off ^ rswz);
            bf16x4 e4 = *(const bf16x4*)pp;
            bf16x4 g4 = *(const bf16x4*)(gr + (off >> 1));
            f32x4 av;
            bf16x4 pb;
            #pragma unroll
            for (int r2 = 0; r2 < 4; ++r2) {
                float v = (float)e4[r2] * (float)g4[r2] * coefR;
                av[r2] = v;
                pb[r2] = (__bf16)v;
            }
            __builtin_nontemporal_store(av, (f32x4*)(ar + (off >> 1)));
            *(bf16x4*)pp = pb;
        }
    }

    // ---- PV: 8 waves = 2q x 4d; V chunks register-pipelined ----
    const int dh = w & 3;
    const int vrow = dh * 16 + l15;
    const int vswz = (vrow & 7) << 4;
    f32x4 cacc = {0.f, 0.f, 0.f, 0.f};
    const __bf16* vcp = vt + ((size_t)(b * HH + h) * 64 + srow) * SS + scol;
    bf16x8 vreg = *(const bf16x8*)vcp;                     // chunk 0
    for (int c = 0; c < 16; ++c) {
        __syncthreads();                                   // KV free / P gated
        *(bf16x8*)(KVb + sdst) = vreg;
        __syncthreads();                                   // KV ready
        if (c + 1 < 16)
            vreg = *(const bf16x8*)(vcp + (c + 1) * 64);
        #pragma unroll
        for (int ks = 0; ks < 2; ++ks) {
            bf16x8 pa = *(const bf16x8*)(Pb + prow * 2048
                          + ((c * 128 + ks * 64 + lg * 16) ^ pswz));
            bf16x8 vv = *(const bf16x8*)(KVb + vrow * 128 + ((ks * 64 + lg * 16) ^ vswz));
            cacc = mfma16(pa, vv, cacc);
        }
    }

    // ---- epilogue: coef already folded; write ctx hi/lo ----
    #pragma unroll
    for (int r = 0; r < 4; ++r) {
        const int row = qsub * 16 + lg * 4 + r;
        float x = cacc[r];
        __bf16 hv = (__bf16)x;
        size_t idx = ((size_t)b * SS + q0 + row) * DM + h * 64 + dh * 16 + l15;
        chi[idx] = hv;
        clo[idx] = (__bf16)(x - (float)hv);
    }
}

extern "C" void kernel_launch(void* const* d_in, const int* in_sizes, int n_in,
                              void* d_out, int out_size, void* d_ws, size_t ws_size,
                              hipStream_t stream) {
    const float* q    = (const float*)d_in[0];
    const float* k    = (const float*)d_in[1];
    const float* v    = (const float*)d_in[2];
    const float* mask = (const float*)d_in[3];
    const float* adj  = (const float*)d_in[4];
    const float* dist = (const float*)d_in[5];
    const float* Wq   = (const float*)d_in[6];
    const float* bq   = (const float*)d_in[7];
    const float* Wk   = (const float*)d_in[8];
    const float* bk   = (const float*)d_in[9];
    const float* Wv   = (const float*)d_in[10];
    const float* bv   = (const float*)d_in[11];
    const float* Wo   = (const float*)d_in[12];
    const float* bo   = (const float*)d_in[13];

    const size_t NT = (size_t)BB * SS * DM;   // 4,194,304
    const size_t WN = 512 * 512;
    const size_t NSS = (size_t)BB * SS * SS;  // 8,388,608
    __bf16* wth = (__bf16*)d_ws;
    __bf16* wtl = wth + 4 * WN;
    __bf16* qhb = wtl + 4 * WN;
    __bf16* khb = qhb + NT;
    __bf16* vtb = khb + NT;
    __bf16* chi = vtb + NT;
    __bf16* clo = chi + NT;
    __bf16* Gg  = clo + NT;
    float* rowILg = (float*)(Gg + NSS);

    float* outp = (float*)d_out;
    float* attn = outp + NT;

    wconv<<<dim3(8, 8, 4), 256, 0, stream>>>(Wq, Wk, Wv, Wo, wth, wtl);

    gprep<<<2048, 256, 0, stream>>>(mask, adj, dist, Gg, rowILg);

    gemm_tile<0><<<dim3(12, 64), 256, 0, stream>>>(
        q, k, v, nullptr, nullptr, wth, wtl, bq, bk, bv,
        nullptr, qhb, khb, vtb);

    attn10<<<2048, 512, 0, stream>>>(qhb, khb, vtb, mask, Gg, rowILg, attn, chi, clo);

    gemm_tile<1><<<dim3(4, 64), 256, 0, stream>>>(
        nullptr, nullptr, nullptr, chi, clo, wth, wtl, bo, nullptr, nullptr,
        outp, nullptr, nullptr, nullptr);
}